// Round 7
// baseline (2633.255 us; speedup 1.0000x reference)
//
#include <hip/hip_runtime.h>
#include <math.h>

#define B_DIM 2048
#define V_DIM 4096
#define H_DIM 1024

// fp32 accumulation emulating OpenBLAS sgemm GEBP: strictly k-sequential FMA
// within KC=384 panels, panel partials combined by fold-left fp32 add in
// ascending panel order. (VERIFIED bit-exact through round 6 — arithmetic
// order load-bearing; do not alter. fmaf(w,h,acc) == fmaf(h,w,acc) bitwise.)
//
// Round 11: barrier-free, LDS-free GEMMs. Round-6 analysis: LDS pipe at 75%,
// VALU at 65%, stalls from per-tile barrier convergence + post-barrier
// A-load latency bursts at 4-5 waves/SIMD. Working sets are cache-hot
// (W panel <= 1.5 MB -> L2; ~8.5 KB per 16-k body -> L1), so staging through
// LDS no longer pays for its barriers. Both GEMMs now read one operand as
// 16-lane-broadcast float4 along k (A / W-rows) and the other as coalesced
// 256B row spans per k (W k-rows / hT k-rows). Zero barriers, zero LDS.
// Same per-element k-ascending FMA chain -> bit-exact.
// transpose fused into combine_h (writes h and hT; saves 3 dispatches).
#define BM 128
#define BN 128
#define KC 384            // OpenBLAS SGEMM_DEFAULT_Q
#define NPANEL_H 11       // V = 10*384 + 256
#define NPANEL_V 3        // H = 2*384 + 256

enum { ACC_NONE = 0, ACC_PREACT = 1, ACC_BIAS = 2 };

// ---------------------------------------------------------------------------
// h-side panel GEMM: P[pan][b][j] = sum_{k in panel} A[b,k] * W[k,j]
// A: float4 along k, 16-lane broadcast. W: per-k row spans, coalesced.
// No LDS, no barriers.
// ---------------------------------------------------------------------------
__global__ __launch_bounds__(256) void gemm_h_panel(
    const float* __restrict__ A,    // [B_DIM, V_DIM]
    const float* __restrict__ W,    // [V_DIM, H_DIM]
    float* __restrict__ P0,         // panel 0 output [B_DIM, H_DIM]
    float* __restrict__ Prest)      // panels 1.. [NPANEL_H-1][B_DIM, H_DIM]
{
    const int bn  = blockIdx.x * BN;
    const int bm  = blockIdx.y * BM;
    const int pan = blockIdx.z;
    const int k0  = pan * KC;
    const int klen = (V_DIM - k0 < KC) ? (V_DIM - k0) : KC;  // 384 or 256

    const int t  = threadIdx.x;
    const int tx = t & 15;
    const int ty = t >> 4;

    const float* A0 = A + (size_t)(bm + ty * 4) * V_DIM + k0;
    const float* A1 = A0 + (size_t)64 * V_DIM;
    const float* Wk = W + (size_t)k0 * H_DIM + bn;   // panel's first W row

    float part[8][8];
#pragma unroll
    for (int i = 0; i < 8; i++)
#pragma unroll
        for (int j = 0; j < 8; j++) part[i][j] = 0.0f;

    for (int kt = 0; kt < klen; kt += 16) {   // klen % 16 == 0 always
#pragma unroll
        for (int q = 0; q < 4; ++q) {
            const int kb = kt + q * 4;
            float ak[4][8];   // [s][i], compile-time indices after unroll
#pragma unroll
            for (int i = 0; i < 4; i++) {
                float4 v0 = *(const float4*)(A0 + (size_t)i * V_DIM + kb);
                float4 v1 = *(const float4*)(A1 + (size_t)i * V_DIM + kb);
                ak[0][i] = v0.x; ak[1][i] = v0.y; ak[2][i] = v0.z; ak[3][i] = v0.w;
                ak[0][i + 4] = v1.x; ak[1][i + 4] = v1.y; ak[2][i + 4] = v1.z; ak[3][i + 4] = v1.w;
            }
#pragma unroll
            for (int s = 0; s < 4; ++s) {
                const float* Wrow = Wk + (size_t)(kb + s) * H_DIM;
                float4 ya = *(const float4*)(Wrow + tx * 4);
                float4 yb = *(const float4*)(Wrow + 64 + tx * 4);
                float bb[8] = {ya.x, ya.y, ya.z, ya.w, yb.x, yb.y, yb.z, yb.w};
#pragma unroll
                for (int i = 0; i < 8; i++)
#pragma unroll
                    for (int j = 0; j < 8; j++)
                        part[i][j] = fmaf(ak[s][i], bb[j], part[i][j]);
            }
        }
    }

    float* Pout = (pan == 0) ? P0 : (Prest + (size_t)(pan - 1) * B_DIM * H_DIM);
#pragma unroll
    for (int i = 0; i < 8; i++) {
        const int row = bm + ((i < 4) ? (ty * 4 + i) : (64 + ty * 4 + (i - 4)));
        float4 lo, hi;
        lo.x = part[i][0]; lo.y = part[i][1]; lo.z = part[i][2]; lo.w = part[i][3];
        hi.x = part[i][4]; hi.y = part[i][5]; hi.z = part[i][6]; hi.w = part[i][7];
        *(float4*)(&Pout[(size_t)row * H_DIM + bn + tx * 4])      = lo;
        *(float4*)(&Pout[(size_t)row * H_DIM + bn + 64 + tx * 4]) = hi;
    }
}

// ---------------------------------------------------------------------------
// v-side panel GEMM (mirror): Q[i][b] = sum_k W[i,k] * hT[k,b], stored to
// P[pan][b][i]. W: float4 along k, 16-lane broadcast. hT: per-k row spans,
// coalesced. No LDS, no barriers. Same k-ascending chain as h@W^T.
// ---------------------------------------------------------------------------
__global__ __launch_bounds__(256) void gemm_vT_panel(
    const float* __restrict__ Wm,   // [V_DIM, H_DIM]
    const float* __restrict__ hT,   // [H_DIM, B_DIM]
    float* __restrict__ P0,         // panel 0 output [B_DIM, V_DIM]
    float* __restrict__ Prest)      // panels 1.. [NPANEL_V-1][B_DIM, V_DIM]
{
    const int bi  = blockIdx.x * BM;   // V rows (output i)
    const int bb0 = blockIdx.y * BN;   // B cols (output b)
    const int pan = blockIdx.z;
    const int k0  = pan * KC;
    const int klen = (H_DIM - k0 < KC) ? (H_DIM - k0) : KC;  // 384 or 256

    const int t  = threadIdx.x;
    const int tx = t & 15;
    const int ty = t >> 4;

    const float* W0 = Wm + (size_t)(bi + ty * 4) * H_DIM + k0;
    const float* W1 = W0 + (size_t)64 * H_DIM;
    const float* Hk = hT + (size_t)k0 * B_DIM + bb0;  // panel's first hT row

    float part[8][8];   // [i][j]: i = V-row, j = b-col
#pragma unroll
    for (int i = 0; i < 8; i++)
#pragma unroll
        for (int j = 0; j < 8; j++) part[i][j] = 0.0f;

    for (int kt = 0; kt < klen; kt += 16) {
#pragma unroll
        for (int q = 0; q < 4; ++q) {
            const int kb = kt + q * 4;
            float ak[4][8];   // [s][i] from W
#pragma unroll
            for (int i = 0; i < 4; i++) {
                float4 v0 = *(const float4*)(W0 + (size_t)i * H_DIM + kb);
                float4 v1 = *(const float4*)(W1 + (size_t)i * H_DIM + kb);
                ak[0][i] = v0.x; ak[1][i] = v0.y; ak[2][i] = v0.z; ak[3][i] = v0.w;
                ak[0][i + 4] = v1.x; ak[1][i + 4] = v1.y; ak[2][i + 4] = v1.z; ak[3][i + 4] = v1.w;
            }
#pragma unroll
            for (int s = 0; s < 4; ++s) {
                const float* Hrow = Hk + (size_t)(kb + s) * B_DIM;
                float4 ya = *(const float4*)(Hrow + tx * 4);
                float4 yb = *(const float4*)(Hrow + 64 + tx * 4);
                float bb[8] = {ya.x, ya.y, ya.z, ya.w, yb.x, yb.y, yb.z, yb.w};
#pragma unroll
                for (int i = 0; i < 8; i++)
#pragma unroll
                    for (int j = 0; j < 8; j++)
                        part[i][j] = fmaf(ak[s][i], bb[j], part[i][j]);
            }
        }
    }

    float* Pout = (pan == 0) ? P0 : (Prest + (size_t)(pan - 1) * B_DIM * V_DIM);
#pragma unroll
    for (int j = 0; j < 8; j++) {
        const int bcol = bb0 + ((j < 4) ? (tx * 4 + j) : (64 + tx * 4 + (j - 4)));
        float4 lo, hi;
        lo.x = part[0][j]; lo.y = part[1][j]; lo.z = part[2][j]; lo.w = part[3][j];
        hi.x = part[4][j]; hi.y = part[5][j]; hi.z = part[6][j]; hi.w = part[7][j];
        *(float4*)(&Pout[(size_t)bcol * V_DIM + bi + ty * 4])      = lo;
        *(float4*)(&Pout[(size_t)bcol * V_DIM + bi + 64 + ty * 4]) = hi;
    }
}

// ---------------------------------------------------------------------------
// h-side combine: tot = ((p0+p1)+...)+p10 ascending (bit-exact fold), then
// pre = bh + tot; h = (sigmoid(pre) > U). Also writes hT[c][b] = h (fused
// transpose for the following v-side GEMM). Hout may alias P0.
// ---------------------------------------------------------------------------
__global__ __launch_bounds__(256) void combine_h(
    const float* P0,               // [B_DIM, H_DIM] (may alias Hout)
    const float* __restrict__ Prest,
    const float* __restrict__ bh,
    const float* __restrict__ U,
    float* Hout,
    float* __restrict__ hTout,     // [H_DIM, B_DIM]
    double* __restrict__ acc,      // direct store (single writer) or nullptr
    const int mode)
{
    const int b = blockIdx.x;
    const int c = threadIdx.x * 4;
    const size_t BH  = (size_t)B_DIM * H_DIM;
    const size_t off = (size_t)b * H_DIM + c;

    float4 tot = *(const float4*)(P0 + off);
#pragma unroll
    for (int p = 1; p < NPANEL_H; p++) {
        float4 q = *(const float4*)(Prest + (size_t)(p - 1) * BH + off);
        tot.x += q.x; tot.y += q.y; tot.z += q.z; tot.w += q.w;
    }
    float4 bias = *(const float4*)(bh + c);
    float4 u    = *(const float4*)(U + off);

    float pre[4] = {bias.x + tot.x, bias.y + tot.y, bias.z + tot.z, bias.w + tot.w};
    float bb[4]  = {bias.x, bias.y, bias.z, bias.w};
    float uu[4]  = {u.x, u.y, u.z, u.w};
    float hv[4];
#pragma unroll
    for (int j = 0; j < 4; j++) {
        float pp = 1.0f / (1.0f + expf(-pre[j]));
        hv[j] = (pp > uu[j]) ? 1.0f : 0.0f;
    }
    float4 hout; hout.x = hv[0]; hout.y = hv[1]; hout.z = hv[2]; hout.w = hv[3];
    *(float4*)(Hout + off) = hout;

    // fused transpose: hT[c+e][b] = hv[e]
#pragma unroll
    for (int e = 0; e < 4; e++)
        hTout[(size_t)(c + e) * B_DIM + b] = hv[e];

    if (mode != ACC_NONE) {
        double s = 0.0;
#pragma unroll
        for (int j = 0; j < 4; j++) {
            if (mode == ACC_PREACT) s += (double)hv[j] * (double)pre[j];
            else                    s += (double)hv[j] * (double)bb[j];
        }
#pragma unroll
        for (int offl = 32; offl >= 1; offl >>= 1) s += __shfl_xor(s, offl, 64);
        __shared__ double red[4];
        if ((threadIdx.x & 63) == 0) red[threadIdx.x >> 6] = s;
        __syncthreads();
        if (threadIdx.x == 0) acc[b] = red[0] + red[1] + red[2] + red[3];
    }
}

// ---------------------------------------------------------------------------
// v-side combine: tot = (p0+p1)+p2 ascending; pre = bv + tot; v = (sig > U).
// Vout may alias P0. One block per row; 16 cols/thread in 4 chunks.
// ---------------------------------------------------------------------------
__global__ __launch_bounds__(256) void combine_v(
    const float* P0,               // [B_DIM, V_DIM] (may alias Vout)
    const float* __restrict__ Prest,
    const float* __restrict__ bv,
    const float* __restrict__ U,
    float* Vout,
    double* __restrict__ acc,
    const int mode)
{
    const int b = blockIdx.x;
    const size_t BV = (size_t)B_DIM * V_DIM;
    double s = 0.0;

#pragma unroll
    for (int ch = 0; ch < 4; ++ch) {
        const int c = ch * 1024 + threadIdx.x * 4;
        const size_t off = (size_t)b * V_DIM + c;
        float4 tot = *(const float4*)(P0 + off);
        float4 q1  = *(const float4*)(Prest + off);
        float4 q2  = *(const float4*)(Prest + BV + off);
        tot.x += q1.x; tot.y += q1.y; tot.z += q1.z; tot.w += q1.w;
        tot.x += q2.x; tot.y += q2.y; tot.z += q2.z; tot.w += q2.w;

        float4 bias = *(const float4*)(bv + c);
        float4 u4   = *(const float4*)(U + off);
        float pre[4] = {bias.x + tot.x, bias.y + tot.y, bias.z + tot.z, bias.w + tot.w};
        float uu[4]  = {u4.x, u4.y, u4.z, u4.w};
        float vs[4];
#pragma unroll
        for (int j = 0; j < 4; j++) {
            float pp = 1.0f / (1.0f + expf(-pre[j]));
            vs[j] = (pp > uu[j]) ? 1.0f : 0.0f;
            if (mode == ACC_PREACT) s += (double)vs[j] * (double)pre[j];
        }
        float4 vst; vst.x = vs[0]; vst.y = vs[1]; vst.z = vs[2]; vst.w = vs[3];
        *(float4*)(Vout + off) = vst;
    }

    if (mode != ACC_NONE) {
#pragma unroll
        for (int offl = 32; offl >= 1; offl >>= 1) s += __shfl_xor(s, offl, 64);
        __shared__ double red[4];
        if ((threadIdx.x & 63) == 0) red[threadIdx.x >> 6] = s;
        __syncthreads();
        if (threadIdx.x == 0) acc[b] = red[0] + red[1] + red[2] + red[3];
    }
}

// out[b] = sum_i X[b,i] * w[i] in fp64 (score term; does not feed sampling)
__global__ __launch_bounds__(256) void rowdot_kernel(
    const float* __restrict__ X, const float* __restrict__ w,
    double* __restrict__ out, const int N)
{
    const int b = blockIdx.x;
    const float* row = X + (size_t)b * N;
    double s = 0.0;
    for (int i = threadIdx.x; i < N / 4; i += blockDim.x) {
        float4 x = ((const float4*)row)[i];
        float4 ww = ((const float4*)w)[i];
        s = fma((double)x.x, (double)ww.x, s);
        s = fma((double)x.y, (double)ww.y, s);
        s = fma((double)x.z, (double)ww.z, s);
        s = fma((double)x.w, (double)ww.w, s);
    }
#pragma unroll
    for (int off = 32; off >= 1; off >>= 1) s += __shfl_xor(s, off, 64);
    __shared__ double red[4];
    if ((threadIdx.x & 63) == 0) red[threadIdx.x >> 6] = s;
    __syncthreads();
    if (threadIdx.x == 0) out[b] = red[0] + red[1] + red[2] + red[3];
}

__global__ void finalize_kernel(const double* __restrict__ vb,
                                const double* __restrict__ accpos,
                                const double* __restrict__ acchb,
                                const double* __restrict__ accneg,
                                float* __restrict__ out)
{
    int b = blockIdx.x * blockDim.x + threadIdx.x;
    if (b < B_DIM) out[b] = (float)(vb[b] + accpos[b] - acchb[b] - accneg[b]);
}

extern "C" void kernel_launch(void* const* d_in, const int* in_sizes, int n_in,
                              void* d_out, int out_size, void* d_ws, size_t ws_size,
                              hipStream_t stream) {
    (void)in_sizes; (void)n_in; (void)out_size; (void)ws_size;
    const float* visible = (const float*)d_in[0];
    const float* b_v     = (const float*)d_in[1];
    const float* b_h     = (const float*)d_in[2];
    const float* W       = (const float*)d_in[3];
    const float* u_h0    = (const float*)d_in[4];
    const float* u_v     = (const float*)d_in[5];  // [3, B, V]
    const float* u_h     = (const float*)d_in[6];  // [2, B, H]
    float* out = (float*)d_out;

    float* v_buf   = (float*)d_ws;                               // B*V floats
    float* h_buf   = v_buf + (size_t)B_DIM * V_DIM;              // B*H floats
    double* acc_pos = (double*)(h_buf + (size_t)B_DIM * H_DIM);  // B doubles
    double* acc_hb  = acc_pos + B_DIM;
    double* acc_neg = acc_hb + B_DIM;
    double* vb      = acc_neg + B_DIM;
    // shared extra-panel region: max(10*B*H, 2*B*V) = 20,971,520 floats (~84 MB)
    float* Pextra   = (float*)(vb + B_DIM);
    // hT [H_DIM, B_DIM] after Pextra (~8 MB); total ws ~134 MB (proven size)
    float* hT       = Pextra + (size_t)10 * B_DIM * H_DIM;

    dim3 blk(256);
    dim3 gh(H_DIM / BN, B_DIM / BM, NPANEL_H);   // 8 x 16 x 11 = 1408 blocks
    dim3 gv(V_DIM / BM, B_DIM / BN, NPANEL_V);   // 32 x 16 x 3 = 1536 blocks
    dim3 gc(B_DIM);

    rowdot_kernel<<<B_DIM, blk, 0, stream>>>(visible, b_v, vb, V_DIM);

    const size_t UV = (size_t)B_DIM * V_DIM;
    const size_t UH = (size_t)B_DIM * H_DIM;

    // positive phase: h | data, + sum h*pre
    gemm_h_panel<<<gh, blk, 0, stream>>>(visible, W, h_buf, Pextra);
    combine_h<<<gc, blk, 0, stream>>>(h_buf, Pextra, b_h, u_h0, h_buf, hT, acc_pos, ACC_PREACT);
    // k=0
    gemm_vT_panel<<<gv, blk, 0, stream>>>(W, hT, v_buf, Pextra);
    combine_v<<<gc, blk, 0, stream>>>(v_buf, Pextra, b_v, u_v + 0 * UV, v_buf, nullptr, ACC_NONE);
    // k=1
    gemm_h_panel<<<gh, blk, 0, stream>>>(v_buf, W, h_buf, Pextra);
    combine_h<<<gc, blk, 0, stream>>>(h_buf, Pextra, b_h, u_h + 0 * UH, h_buf, hT, nullptr, ACC_NONE);
    // k=2
    gemm_vT_panel<<<gv, blk, 0, stream>>>(W, hT, v_buf, Pextra);
    combine_v<<<gc, blk, 0, stream>>>(v_buf, Pextra, b_v, u_v + 1 * UV, v_buf, nullptr, ACC_NONE);
    // k=3: + h.b_h of final h
    gemm_h_panel<<<gh, blk, 0, stream>>>(v_buf, W, h_buf, Pextra);
    combine_h<<<gc, blk, 0, stream>>>(h_buf, Pextra, b_h, u_h + 1 * UH, h_buf, hT, acc_hb, ACC_BIAS);
    // k=4: + sum_i v*pre (negative score)
    gemm_vT_panel<<<gv, blk, 0, stream>>>(W, hT, v_buf, Pextra);
    combine_v<<<gc, blk, 0, stream>>>(v_buf, Pextra, b_v, u_v + 2 * UV, v_buf, acc_neg, ACC_PREACT);

    finalize_kernel<<<(B_DIM + 255) / 256, blk, 0, stream>>>(vb, acc_pos, acc_hb, acc_neg, out);
}

// Round 8
// 2155.208 us; speedup vs baseline: 1.2218x; 1.2218x over previous
//
#include <hip/hip_runtime.h>
#include <math.h>

#define B_DIM 2048
#define V_DIM 4096
#define H_DIM 1024

// fp32 accumulation emulating OpenBLAS sgemm GEBP: strictly k-sequential FMA
// within KC=384 panels, panel partials combined by fold-left fp32 add in
// ascending panel order. (VERIFIED bit-exact through round 7 — arithmetic
// order load-bearing; do not alter. fmaf(w,h,acc) == fmaf(h,w,acc) bitwise.)
//
// Round 12: barrier-FREE but staging-KEPT GEMMs. Evidence: round 6 (LDS
// staging + barriers) = 251/216 us @ VALU 65%; round 7 (no staging, no
// barriers) = 600 us @ VALU 21% (L1 thrash, raw latency). Synthesis: each
// wave stages its own private 16x32 column-slice of the B-operand via
// global_load_lds (2 buf x 4 waves x 2 KB = 16 KB LDS) — no cross-wave
// sharing -> zero s_barrier. Per-wave counted s_waitcnt vmcnt(10) (in-order
// vmem retirement: ops younger than tile-it's 2 GLDs = 8 A-prefetch + 2
// next-GLD = 10; final iter vmcnt(8)). A-operand q0 prefetched across the
// wait. Same per-element k-ascending FMA chain -> bit-exact.
#define BM 128
#define BN 128
#define BK 16
#define KC 384            // OpenBLAS SGEMM_DEFAULT_Q
#define NPANEL_H 11       // V = 10*384 + 256
#define NPANEL_V 3        // H = 2*384 + 256

enum { ACC_NONE = 0, ACC_PREACT = 1, ACC_BIAS = 2 };

#define GLD_LDS16(gsrc, ldst)                                                  \
    __builtin_amdgcn_global_load_lds(                                          \
        (const __attribute__((address_space(1))) void*)(gsrc),                 \
        (__attribute__((address_space(3))) void*)(ldst), 16, 0, 0)

// ---------------------------------------------------------------------------
// h-side panel GEMM: P[pan][b][j] = sum_{k in panel} A[b,k] * W[k,j]
// Wave w owns output cols [w*32, w*32+32); stages W[k][those cols] into its
// private LDS slice. A read direct from global (4-lane broadcast), q0
// prefetched across the per-wave vmcnt wait. No barriers.
// ---------------------------------------------------------------------------
__global__ __launch_bounds__(256) void gemm_h_panel(
    const float* __restrict__ A,    // [B_DIM, V_DIM]
    const float* __restrict__ W,    // [V_DIM, H_DIM]
    float* __restrict__ P0,         // panel 0 output [B_DIM, H_DIM]
    float* __restrict__ Prest)      // panels 1.. [NPANEL_H-1][B_DIM, H_DIM]
{
    __shared__ float Bs[2][4][BK][32];   // 16 KB, wave-private slices

    const int bn  = blockIdx.x * BN;
    const int bm  = blockIdx.y * BM;
    const int pan = blockIdx.z;
    const int k0  = pan * KC;
    const int klen = (V_DIM - k0 < KC) ? (V_DIM - k0) : KC;  // 384 or 256
    const int T = klen / BK;                                  // 24 or 16

    const int t    = threadIdx.x;
    const int w    = t >> 6;          // wave 0..3
    const int lane = t & 63;
    const int rg   = lane >> 2;       // 0..15: row group
    const int cg   = lane & 3;        // 0..3 : col group within wave's 32

    // staging source: lane l covers k-row (l>>3), col (l&7)*4 of each 8x32 issue
    const int sr = lane >> 3;         // 0..7
    const int sc = (lane & 7) * 4;    // 0,4,..,28
    const float* Wsrc = W + (size_t)(k0 + sr) * H_DIM + bn + w * 32 + sc;

    // A row bases: this thread's 8 output rows (4-lane broadcast per address)
    const float* A0 = A + (size_t)(bm + rg * 4) * V_DIM + k0;
    const float* A1 = A0 + (size_t)64 * V_DIM;

    float part[8][8];
#pragma unroll
    for (int i = 0; i < 8; i++)
#pragma unroll
        for (int j = 0; j < 8; j++) part[i][j] = 0.0f;

    // prologue: stage tile 0 into buf 0 (this wave's slice only)
    GLD_LDS16(Wsrc,               &Bs[0][w][0][0]);
    GLD_LDS16(Wsrc + 8 * H_DIM,   &Bs[0][w][8][0]);
    asm volatile("" ::: "memory");   // pin issue order: GLDs before ap loads
    float4 ap[8];                     // A prefetch for tile 0, q0
#pragma unroll
    for (int i = 0; i < 4; i++) {
        ap[i]     = *(const float4*)(A0 + (size_t)i * V_DIM);
        ap[i + 4] = *(const float4*)(A1 + (size_t)i * V_DIM);
    }

    int cur = 0;
    for (int it = 0; it < T; ++it) {
        if (it + 1 < T) {
            const float* Ws = Wsrc + (size_t)(it + 1) * BK * H_DIM;
            GLD_LDS16(Ws,             &Bs[cur ^ 1][w][0][0]);
            GLD_LDS16(Ws + 8 * H_DIM, &Bs[cur ^ 1][w][8][0]);
            // younger than tile-it GLDs: 8 ap + 2 next-GLD = 10
            asm volatile("s_waitcnt vmcnt(10)" ::: "memory");
        } else {
            asm volatile("s_waitcnt vmcnt(8)" ::: "memory");
        }
        const int kb = it * BK;
#pragma unroll
        for (int q = 0; q < 4; ++q) {
            float ak[4][8];   // [s][i]
            if (q == 0) {
#pragma unroll
                for (int i = 0; i < 4; i++) {
                    ak[0][i] = ap[i].x; ak[1][i] = ap[i].y; ak[2][i] = ap[i].z; ak[3][i] = ap[i].w;
                    ak[0][i + 4] = ap[i + 4].x; ak[1][i + 4] = ap[i + 4].y;
                    ak[2][i + 4] = ap[i + 4].z; ak[3][i + 4] = ap[i + 4].w;
                }
            } else {
#pragma unroll
                for (int i = 0; i < 4; i++) {
                    float4 v0 = *(const float4*)(A0 + (size_t)i * V_DIM + kb + q * 4);
                    float4 v1 = *(const float4*)(A1 + (size_t)i * V_DIM + kb + q * 4);
                    ak[0][i] = v0.x; ak[1][i] = v0.y; ak[2][i] = v0.z; ak[3][i] = v0.w;
                    ak[0][i + 4] = v1.x; ak[1][i + 4] = v1.y; ak[2][i + 4] = v1.z; ak[3][i + 4] = v1.w;
                }
            }
#pragma unroll
            for (int s = 0; s < 4; ++s) {
                const int k = q * 4 + s;
                float4 ya = *(const float4*)(&Bs[cur][w][k][cg * 4]);
                float4 yb = *(const float4*)(&Bs[cur][w][k][16 + cg * 4]);
                float bb[8] = {ya.x, ya.y, ya.z, ya.w, yb.x, yb.y, yb.z, yb.w};
#pragma unroll
                for (int i = 0; i < 8; i++)
#pragma unroll
                    for (int j = 0; j < 8; j++)
                        part[i][j] = fmaf(ak[s][i], bb[j], part[i][j]);
            }
        }
        if (it + 1 < T) {   // A prefetch for next tile's q0
            const int kn = (it + 1) * BK;
#pragma unroll
            for (int i = 0; i < 4; i++) {
                ap[i]     = *(const float4*)(A0 + (size_t)i * V_DIM + kn);
                ap[i + 4] = *(const float4*)(A1 + (size_t)i * V_DIM + kn);
            }
        }
        cur ^= 1;
    }

    float* Pout = (pan == 0) ? P0 : (Prest + (size_t)(pan - 1) * B_DIM * H_DIM);
#pragma unroll
    for (int i = 0; i < 8; i++) {
        const int row = bm + ((i < 4) ? (rg * 4 + i) : (64 + rg * 4 + (i - 4)));
        float4 lo, hi;
        lo.x = part[i][0]; lo.y = part[i][1]; lo.z = part[i][2]; lo.w = part[i][3];
        hi.x = part[i][4]; hi.y = part[i][5]; hi.z = part[i][6]; hi.w = part[i][7];
        *(float4*)(&Pout[(size_t)row * H_DIM + bn + w * 32 + cg * 4])      = lo;
        *(float4*)(&Pout[(size_t)row * H_DIM + bn + w * 32 + 16 + cg * 4]) = hi;
    }
}

// ---------------------------------------------------------------------------
// v-side panel GEMM (mirror): Q[i][b] = sum_k W[i,k] * hT[k,b] -> P[pan][b][i].
// Wave w owns b-cols [w*32, w*32+32); stages hT[k][those cols] privately.
// W rows read direct from global (4-lane broadcast), q0 prefetched.
// ---------------------------------------------------------------------------
__global__ __launch_bounds__(256) void gemm_vT_panel(
    const float* __restrict__ Wm,   // [V_DIM, H_DIM]
    const float* __restrict__ hT,   // [H_DIM, B_DIM]
    float* __restrict__ P0,         // panel 0 output [B_DIM, V_DIM]
    float* __restrict__ Prest)      // panels 1.. [NPANEL_V-1][B_DIM, V_DIM]
{
    __shared__ float Bs[2][4][BK][32];   // 16 KB

    const int bi  = blockIdx.x * BM;   // V rows (output i)
    const int bb0 = blockIdx.y * BN;   // B cols (output b)
    const int pan = blockIdx.z;
    const int k0  = pan * KC;
    const int klen = (H_DIM - k0 < KC) ? (H_DIM - k0) : KC;  // 384 or 256
    const int T = klen / BK;

    const int t    = threadIdx.x;
    const int w    = t >> 6;
    const int lane = t & 63;
    const int rg   = lane >> 2;
    const int cg   = lane & 3;

    const int sr = lane >> 3;
    const int sc = (lane & 7) * 4;
    const float* Hsrc = hT + (size_t)(k0 + sr) * B_DIM + bb0 + w * 32 + sc;

    const float* W0 = Wm + (size_t)(bi + rg * 4) * H_DIM + k0;
    const float* W1 = W0 + (size_t)64 * H_DIM;

    float part[8][8];   // [i][j]: i = V-row, j = b-col
#pragma unroll
    for (int i = 0; i < 8; i++)
#pragma unroll
        for (int j = 0; j < 8; j++) part[i][j] = 0.0f;

    GLD_LDS16(Hsrc,               &Bs[0][w][0][0]);
    GLD_LDS16(Hsrc + 8 * B_DIM,   &Bs[0][w][8][0]);
    asm volatile("" ::: "memory");
    float4 ap[8];
#pragma unroll
    for (int i = 0; i < 4; i++) {
        ap[i]     = *(const float4*)(W0 + (size_t)i * H_DIM);
        ap[i + 4] = *(const float4*)(W1 + (size_t)i * H_DIM);
    }

    int cur = 0;
    for (int it = 0; it < T; ++it) {
        if (it + 1 < T) {
            const float* Hs = Hsrc + (size_t)(it + 1) * BK * B_DIM;
            GLD_LDS16(Hs,             &Bs[cur ^ 1][w][0][0]);
            GLD_LDS16(Hs + 8 * B_DIM, &Bs[cur ^ 1][w][8][0]);
            asm volatile("s_waitcnt vmcnt(10)" ::: "memory");
        } else {
            asm volatile("s_waitcnt vmcnt(8)" ::: "memory");
        }
        const int kb = it * BK;
#pragma unroll
        for (int q = 0; q < 4; ++q) {
            float ak[4][8];
            if (q == 0) {
#pragma unroll
                for (int i = 0; i < 4; i++) {
                    ak[0][i] = ap[i].x; ak[1][i] = ap[i].y; ak[2][i] = ap[i].z; ak[3][i] = ap[i].w;
                    ak[0][i + 4] = ap[i + 4].x; ak[1][i + 4] = ap[i + 4].y;
                    ak[2][i + 4] = ap[i + 4].z; ak[3][i + 4] = ap[i + 4].w;
                }
            } else {
#pragma unroll
                for (int i = 0; i < 4; i++) {
                    float4 v0 = *(const float4*)(W0 + (size_t)i * H_DIM + kb + q * 4);
                    float4 v1 = *(const float4*)(W1 + (size_t)i * H_DIM + kb + q * 4);
                    ak[0][i] = v0.x; ak[1][i] = v0.y; ak[2][i] = v0.z; ak[3][i] = v0.w;
                    ak[0][i + 4] = v1.x; ak[1][i + 4] = v1.y; ak[2][i + 4] = v1.z; ak[3][i + 4] = v1.w;
                }
            }
#pragma unroll
            for (int s = 0; s < 4; ++s) {
                const int k = q * 4 + s;
                float4 ya = *(const float4*)(&Bs[cur][w][k][cg * 4]);
                float4 yb = *(const float4*)(&Bs[cur][w][k][16 + cg * 4]);
                float bb[8] = {ya.x, ya.y, ya.z, ya.w, yb.x, yb.y, yb.z, yb.w};
#pragma unroll
                for (int i = 0; i < 8; i++)
#pragma unroll
                    for (int j = 0; j < 8; j++)
                        part[i][j] = fmaf(ak[s][i], bb[j], part[i][j]);
            }
        }
        if (it + 1 < T) {
            const int kn = (it + 1) * BK;
#pragma unroll
            for (int i = 0; i < 4; i++) {
                ap[i]     = *(const float4*)(W0 + (size_t)i * H_DIM + kn);
                ap[i + 4] = *(const float4*)(W1 + (size_t)i * H_DIM + kn);
            }
        }
        cur ^= 1;
    }

    float* Pout = (pan == 0) ? P0 : (Prest + (size_t)(pan - 1) * B_DIM * V_DIM);
#pragma unroll
    for (int j = 0; j < 8; j++) {
        const int bcol = bb0 + w * 32 + ((j < 4) ? (cg * 4 + j) : (16 + cg * 4 + (j - 4)));
        float4 lo, hi;
        lo.x = part[0][j]; lo.y = part[1][j]; lo.z = part[2][j]; lo.w = part[3][j];
        hi.x = part[4][j]; hi.y = part[5][j]; hi.z = part[6][j]; hi.w = part[7][j];
        *(float4*)(&Pout[(size_t)bcol * V_DIM + bi + rg * 4])      = lo;
        *(float4*)(&Pout[(size_t)bcol * V_DIM + bi + 64 + rg * 4]) = hi;
    }
}

// ---------------------------------------------------------------------------
// h-side combine: tot = ((p0+p1)+...)+p10 ascending (bit-exact fold), then
// pre = bh + tot; h = (sigmoid(pre) > U). Also writes hT (fused transpose).
// Hout may alias P0.
// ---------------------------------------------------------------------------
__global__ __launch_bounds__(256) void combine_h(
    const float* P0,               // [B_DIM, H_DIM] (may alias Hout)
    const float* __restrict__ Prest,
    const float* __restrict__ bh,
    const float* __restrict__ U,
    float* Hout,
    float* __restrict__ hTout,     // [H_DIM, B_DIM]
    double* __restrict__ acc,      // direct store (single writer) or nullptr
    const int mode)
{
    const int b = blockIdx.x;
    const int c = threadIdx.x * 4;
    const size_t BH  = (size_t)B_DIM * H_DIM;
    const size_t off = (size_t)b * H_DIM + c;

    float4 tot = *(const float4*)(P0 + off);
#pragma unroll
    for (int p = 1; p < NPANEL_H; p++) {
        float4 q = *(const float4*)(Prest + (size_t)(p - 1) * BH + off);
        tot.x += q.x; tot.y += q.y; tot.z += q.z; tot.w += q.w;
    }
    float4 bias = *(const float4*)(bh + c);
    float4 u    = *(const float4*)(U + off);

    float pre[4] = {bias.x + tot.x, bias.y + tot.y, bias.z + tot.z, bias.w + tot.w};
    float bb[4]  = {bias.x, bias.y, bias.z, bias.w};
    float uu[4]  = {u.x, u.y, u.z, u.w};
    float hv[4];
#pragma unroll
    for (int j = 0; j < 4; j++) {
        float pp = 1.0f / (1.0f + expf(-pre[j]));
        hv[j] = (pp > uu[j]) ? 1.0f : 0.0f;
    }
    float4 hout; hout.x = hv[0]; hout.y = hv[1]; hout.z = hv[2]; hout.w = hv[3];
    *(float4*)(Hout + off) = hout;

    // fused transpose: hT[c+e][b] = hv[e]
#pragma unroll
    for (int e = 0; e < 4; e++)
        hTout[(size_t)(c + e) * B_DIM + b] = hv[e];

    if (mode != ACC_NONE) {
        double s = 0.0;
#pragma unroll
        for (int j = 0; j < 4; j++) {
            if (mode == ACC_PREACT) s += (double)hv[j] * (double)pre[j];
            else                    s += (double)hv[j] * (double)bb[j];
        }
#pragma unroll
        for (int offl = 32; offl >= 1; offl >>= 1) s += __shfl_xor(s, offl, 64);
        __shared__ double red[4];
        if ((threadIdx.x & 63) == 0) red[threadIdx.x >> 6] = s;
        __syncthreads();
        if (threadIdx.x == 0) acc[b] = red[0] + red[1] + red[2] + red[3];
    }
}

// ---------------------------------------------------------------------------
// v-side combine: tot = (p0+p1)+p2 ascending; pre = bv + tot; v = (sig > U).
// Vout may alias P0. One block per row; 16 cols/thread in 4 chunks.
// ---------------------------------------------------------------------------
__global__ __launch_bounds__(256) void combine_v(
    const float* P0,               // [B_DIM, V_DIM] (may alias Vout)
    const float* __restrict__ Prest,
    const float* __restrict__ bv,
    const float* __restrict__ U,
    float* Vout,
    double* __restrict__ acc,
    const int mode)
{
    const int b = blockIdx.x;
    const size_t BV = (size_t)B_DIM * V_DIM;
    double s = 0.0;

#pragma unroll
    for (int ch = 0; ch < 4; ++ch) {
        const int c = ch * 1024 + threadIdx.x * 4;
        const size_t off = (size_t)b * V_DIM + c;
        float4 tot = *(const float4*)(P0 + off);
        float4 q1  = *(const float4*)(Prest + off);
        float4 q2  = *(const float4*)(Prest + BV + off);
        tot.x += q1.x; tot.y += q1.y; tot.z += q1.z; tot.w += q1.w;
        tot.x += q2.x; tot.y += q2.y; tot.z += q2.z; tot.w += q2.w;

        float4 bias = *(const float4*)(bv + c);
        float4 u4   = *(const float4*)(U + off);
        float pre[4] = {bias.x + tot.x, bias.y + tot.y, bias.z + tot.z, bias.w + tot.w};
        float uu[4]  = {u4.x, u4.y, u4.z, u4.w};
        float vs[4];
#pragma unroll
        for (int j = 0; j < 4; j++) {
            float pp = 1.0f / (1.0f + expf(-pre[j]));
            vs[j] = (pp > uu[j]) ? 1.0f : 0.0f;
            if (mode == ACC_PREACT) s += (double)vs[j] * (double)pre[j];
        }
        float4 vst; vst.x = vs[0]; vst.y = vs[1]; vst.z = vs[2]; vst.w = vs[3];
        *(float4*)(Vout + off) = vst;
    }

    if (mode != ACC_NONE) {
#pragma unroll
        for (int offl = 32; offl >= 1; offl >>= 1) s += __shfl_xor(s, offl, 64);
        __shared__ double red[4];
        if ((threadIdx.x & 63) == 0) red[threadIdx.x >> 6] = s;
        __syncthreads();
        if (threadIdx.x == 0) acc[b] = red[0] + red[1] + red[2] + red[3];
    }
}

// out[b] = sum_i X[b,i] * w[i] in fp64 (score term; does not feed sampling)
__global__ __launch_bounds__(256) void rowdot_kernel(
    const float* __restrict__ X, const float* __restrict__ w,
    double* __restrict__ out, const int N)
{
    const int b = blockIdx.x;
    const float* row = X + (size_t)b * N;
    double s = 0.0;
    for (int i = threadIdx.x; i < N / 4; i += blockDim.x) {
        float4 x = ((const float4*)row)[i];
        float4 ww = ((const float4*)w)[i];
        s = fma((double)x.x, (double)ww.x, s);
        s = fma((double)x.y, (double)ww.y, s);
        s = fma((double)x.z, (double)ww.z, s);
        s = fma((double)x.w, (double)ww.w, s);
    }
#pragma unroll
    for (int off = 32; off >= 1; off >>= 1) s += __shfl_xor(s, off, 64);
    __shared__ double red[4];
    if ((threadIdx.x & 63) == 0) red[threadIdx.x >> 6] = s;
    __syncthreads();
    if (threadIdx.x == 0) out[b] = red[0] + red[1] + red[2] + red[3];
}

__global__ void finalize_kernel(const double* __restrict__ vb,
                                const double* __restrict__ accpos,
                                const double* __restrict__ acchb,
                                const double* __restrict__ accneg,
                                float* __restrict__ out)
{
    int b = blockIdx.x * blockDim.x + threadIdx.x;
    if (b < B_DIM) out[b] = (float)(vb[b] + accpos[b] - acchb[b] - accneg[b]);
}

extern "C" void kernel_launch(void* const* d_in, const int* in_sizes, int n_in,
                              void* d_out, int out_size, void* d_ws, size_t ws_size,
                              hipStream_t stream) {
    (void)in_sizes; (void)n_in; (void)out_size; (void)ws_size;
    const float* visible = (const float*)d_in[0];
    const float* b_v     = (const float*)d_in[1];
    const float* b_h     = (const float*)d_in[2];
    const float* W       = (const float*)d_in[3];
    const float* u_h0    = (const float*)d_in[4];
    const float* u_v     = (const float*)d_in[5];  // [3, B, V]
    const float* u_h     = (const float*)d_in[6];  // [2, B, H]
    float* out = (float*)d_out;

    float* v_buf   = (float*)d_ws;                               // B*V floats
    float* h_buf   = v_buf + (size_t)B_DIM * V_DIM;              // B*H floats
    double* acc_pos = (double*)(h_buf + (size_t)B_DIM * H_DIM);  // B doubles
    double* acc_hb  = acc_pos + B_DIM;
    double* acc_neg = acc_hb + B_DIM;
    double* vb      = acc_neg + B_DIM;
    // shared extra-panel region: max(10*B*H, 2*B*V) = 20,971,520 floats (~84 MB)
    float* Pextra   = (float*)(vb + B_DIM);
    // hT [H_DIM, B_DIM] after Pextra (~8 MB); total ws ~134 MB (proven size)
    float* hT       = Pextra + (size_t)10 * B_DIM * H_DIM;

    dim3 blk(256);
    dim3 gh(H_DIM / BN, B_DIM / BM, NPANEL_H);   // 8 x 16 x 11 = 1408 blocks
    dim3 gv(V_DIM / BM, B_DIM / BN, NPANEL_V);   // 32 x 16 x 3 = 1536 blocks
    dim3 gc(B_DIM);

    rowdot_kernel<<<B_DIM, blk, 0, stream>>>(visible, b_v, vb, V_DIM);

    const size_t UV = (size_t)B_DIM * V_DIM;
    const size_t UH = (size_t)B_DIM * H_DIM;

    // positive phase: h | data, + sum h*pre
    gemm_h_panel<<<gh, blk, 0, stream>>>(visible, W, h_buf, Pextra);
    combine_h<<<gc, blk, 0, stream>>>(h_buf, Pextra, b_h, u_h0, h_buf, hT, acc_pos, ACC_PREACT);
    // k=0
    gemm_vT_panel<<<gv, blk, 0, stream>>>(W, hT, v_buf, Pextra);
    combine_v<<<gc, blk, 0, stream>>>(v_buf, Pextra, b_v, u_v + 0 * UV, v_buf, nullptr, ACC_NONE);
    // k=1
    gemm_h_panel<<<gh, blk, 0, stream>>>(v_buf, W, h_buf, Pextra);
    combine_h<<<gc, blk, 0, stream>>>(h_buf, Pextra, b_h, u_h + 0 * UH, h_buf, hT, nullptr, ACC_NONE);
    // k=2
    gemm_vT_panel<<<gv, blk, 0, stream>>>(W, hT, v_buf, Pextra);
    combine_v<<<gc, blk, 0, stream>>>(v_buf, Pextra, b_v, u_v + 1 * UV, v_buf, nullptr, ACC_NONE);
    // k=3: + h.b_h of final h
    gemm_h_panel<<<gh, blk, 0, stream>>>(v_buf, W, h_buf, Pextra);
    combine_h<<<gc, blk, 0, stream>>>(h_buf, Pextra, b_h, u_h + 1 * UH, h_buf, hT, acc_hb, ACC_BIAS);
    // k=4: + sum_i v*pre (negative score)
    gemm_vT_panel<<<gv, blk, 0, stream>>>(W, hT, v_buf, Pextra);
    combine_v<<<gc, blk, 0, stream>>>(v_buf, Pextra, b_v, u_v + 2 * UV, v_buf, acc_neg, ACC_PREACT);

    finalize_kernel<<<(B_DIM + 255) / 256, blk, 0, stream>>>(vb, acc_pos, acc_hb, acc_neg, out);
}